// Round 5
// baseline (593.145 us; speedup 1.0000x reference)
//
#include <hip/hip_runtime.h>
#include <math.h>

#define B_DIM 2048
#define D_DIM 256
#define H1 512
#define H2 256
#define LBL 10
#define M_ROWS (B_DIM * LBL)
#define HCH 256      // H1 half-chunk
#define A1_LD 260    // padded leading dim for A1h
#define KT 16        // k-tile rows staged in LDS
#define NT_D (D_DIM / KT)
#define NT_H (HCH / KT)

__device__ __forceinline__ void acc4(float4& s, const float4 a) {
  s.x += a.x; s.y += a.y; s.z += a.z; s.w += a.w;
}

__device__ __forceinline__ float leaky(float v) { return v > 0.f ? v : 0.01f * v; }

// async global->LDS, 16B per lane; dest = wave-uniform base + lane*16
__device__ __forceinline__ void stage16(const float* g, float* l) {
  __builtin_amdgcn_global_load_lds(
      (const __attribute__((address_space(1))) char*)g,
      (__attribute__((address_space(3))) char*)l, 16, 0, 0);
}

// ---------------- Kernel A: prefix means -> h [B][LBL][D] ----------------
__global__ __launch_bounds__(256) void prefix_kernel(
    const float* __restrict__ x, const int* __restrict__ lens,
    float* __restrict__ h) {
  const int wv = threadIdx.x >> 6;
  const int lane = threadIdx.x & 63;
  const int b = blockIdx.x * 4 + wv;
  const int L = lens[b];
  const int Lm = L - LBL;
  const size_t ts = (size_t)(B_DIM * D_DIM / 4);
  const float4* xb = reinterpret_cast<const float4*>(x) + (size_t)b * (D_DIM / 4) + lane;
  float4 s0 = make_float4(0.f, 0.f, 0.f, 0.f), s1 = s0, s2 = s0, s3 = s0;
  int t = 0;
  for (; t + 8 <= Lm; t += 8) {
    float4 a0 = xb[(size_t)(t + 0) * ts], a1 = xb[(size_t)(t + 1) * ts];
    float4 a2 = xb[(size_t)(t + 2) * ts], a3 = xb[(size_t)(t + 3) * ts];
    float4 a4 = xb[(size_t)(t + 4) * ts], a5 = xb[(size_t)(t + 5) * ts];
    float4 a6 = xb[(size_t)(t + 6) * ts], a7 = xb[(size_t)(t + 7) * ts];
    acc4(s0, a0); acc4(s1, a1); acc4(s2, a2); acc4(s3, a3);
    acc4(s0, a4); acc4(s1, a5); acc4(s2, a6); acc4(s3, a7);
  }
  for (; t < Lm; ++t) acc4(s0, xb[(size_t)t * ts]);
  acc4(s0, s1); acc4(s2, s3); acc4(s0, s2);
  float4* hout = reinterpret_cast<float4*>(h) + (size_t)b * (LBL * D_DIM / 4) + lane;
  #pragma unroll
  for (int k = 0; k < LBL; ++k) {
    const int tt = Lm + k;
    acc4(s0, xb[(size_t)tt * ts]);
    const float inv = 1.0f / (float)(tt + 1);
    float4 o;
    o.x = s0.x * inv; o.y = s0.y * inv; o.z = s0.z * inv; o.w = s0.w * inv;
    hout[(size_t)k * (D_DIM / 4)] = o;
  }
}

// ---------------- Kernel B: fused two-tower MLP, LDS-staged weights --------
// 256 threads, 32 rows/block. rt=tid>>5 (4 rows), nt=tid&31.
// Lane nt owns cols {4nt..4nt+3, 128+4nt..128+4nt+3} of each 256-col panel:
// its two ds_read_b128 per k sit at 16B lane stride -> conflict-free.
__global__ __launch_bounds__(256, 4) void tower_kernel(
    const float* __restrict__ h,
    const float* __restrict__ W1a, const float* __restrict__ b1a,
    const float* __restrict__ W2a, const float* __restrict__ b2a,
    const float* __restrict__ W3a, const float* __restrict__ b3a,
    const float* __restrict__ W1b, const float* __restrict__ b1b,
    const float* __restrict__ W2b, const float* __restrict__ b2b,
    const float* __restrict__ W3b, const float* __restrict__ b3b,
    float* __restrict__ out) {
  __shared__ float Wt[KT][HCH];        // 16 KB weight panel
  __shared__ float A1h[32][A1_LD];     // 33.3 KB layer-1 half activations
  const int tid = threadIdx.x;
  const int lane = tid & 63;
  const int wv = tid >> 6;
  const int rt = tid >> 5;
  const int nt = tid & 31;
  const int r0 = blockIdx.x * 32;
  const float* __restrict__ hr0 = h + (size_t)(r0 + rt * 4) * D_DIM;

  float sigp[4];

  for (int tw = 0; tw < 2; ++tw) {
    const float* __restrict__ W1 = tw ? W1b : W1a;
    const float* __restrict__ B1 = tw ? b1b : b1a;
    const float* __restrict__ W2 = tw ? W2b : W2a;
    const float* __restrict__ B2 = tw ? b2b : b2a;
    const float* __restrict__ W3 = tw ? W3b : W3a;
    const float* __restrict__ B3 = tw ? b3b : b3a;

    float Z[4][8];
    #pragma unroll
    for (int i = 0; i < 4; ++i)
      #pragma unroll
      for (int c = 0; c < 8; ++c)
        Z[i][c] = B2[(c < 4) ? nt * 4 + c : 124 + nt * 4 + c];

    for (int half = 0; half < 2; ++half) {
      const int c0 = half * HCH;

      // ================= layer 1: h[32x256] @ W1[:,c0:c0+256] =============
      float a[4][8];
      #pragma unroll
      for (int i = 0; i < 4; ++i)
        #pragma unroll
        for (int c = 0; c < 8; ++c)
          a[i][c] = B1[c0 + ((c < 4) ? nt * 4 + c : 124 + nt * 4 + c)];

      // stage tile 0
      #pragma unroll
      for (int j = 0; j < 4; ++j) {
        const int r = wv * 4 + j;
        stage16(W1 + (size_t)r * H1 + c0 + lane * 4, &Wt[r][0]);
      }
      float4 hn[4];
      #pragma unroll
      for (int i = 0; i < 4; ++i)
        hn[i] = *reinterpret_cast<const float4*>(hr0 + (size_t)i * D_DIM);

      for (int t = 0; t < NT_D; ++t) {
        __syncthreads();  // Wt tile t visible (vmcnt drained by barrier)
        const int k0 = t * KT;
        #pragma unroll
        for (int k4 = 0; k4 < KT; k4 += 4) {
          float hs4[4][4];
          #pragma unroll
          for (int i = 0; i < 4; ++i) {
            hs4[i][0] = hn[i].x; hs4[i][1] = hn[i].y;
            hs4[i][2] = hn[i].z; hs4[i][3] = hn[i].w;
          }
          int kn = k0 + k4 + 4;
          if (kn > D_DIM - 4) kn = D_DIM - 4;  // clamped prefetch (unused at end)
          #pragma unroll
          for (int i = 0; i < 4; ++i)
            hn[i] = *reinterpret_cast<const float4*>(hr0 + (size_t)i * D_DIM + kn);
          #pragma unroll
          for (int kk = 0; kk < 4; ++kk) {
            const float4* wrow = reinterpret_cast<const float4*>(&Wt[k4 + kk][0]);
            const float4 w0 = wrow[nt];
            const float4 w1 = wrow[32 + nt];
            const float wv8[8] = {w0.x, w0.y, w0.z, w0.w, w1.x, w1.y, w1.z, w1.w};
            #pragma unroll
            for (int i = 0; i < 4; ++i)
              #pragma unroll
              for (int c = 0; c < 8; ++c)
                a[i][c] = fmaf(hs4[i][kk], wv8[c], a[i][c]);
          }
        }
        __syncthreads();  // Wt reads done
        if (t + 1 < NT_D) {
          #pragma unroll
          for (int j = 0; j < 4; ++j) {
            const int r = wv * 4 + j;
            stage16(W1 + (size_t)(k0 + KT + r) * H1 + c0 + lane * 4, &Wt[r][0]);
          }
        }
      }

      // stage W2 tile 0 (Wt free), write A1h, one barrier covers both
      #pragma unroll
      for (int j = 0; j < 4; ++j) {
        const int r = wv * 4 + j;
        stage16(W2 + (size_t)(c0 + r) * H2 + lane * 4, &Wt[r][0]);
      }
      #pragma unroll
      for (int i = 0; i < 4; ++i) {
        float4 lo, hi;
        lo.x = leaky(a[i][0]); lo.y = leaky(a[i][1]);
        lo.z = leaky(a[i][2]); lo.w = leaky(a[i][3]);
        hi.x = leaky(a[i][4]); hi.y = leaky(a[i][5]);
        hi.z = leaky(a[i][6]); hi.w = leaky(a[i][7]);
        *reinterpret_cast<float4*>(&A1h[rt * 4 + i][nt * 4]) = lo;
        *reinterpret_cast<float4*>(&A1h[rt * 4 + i][128 + nt * 4]) = hi;
      }

      // ================= layer 2: A1[32x256] @ W2[c0:c0+256,:] ============
      for (int t = 0; t < NT_H; ++t) {
        __syncthreads();  // Wt tile t (+A1h at t==0) visible
        const int k0 = t * KT;
        #pragma unroll
        for (int k4 = 0; k4 < KT; k4 += 4) {
          float av4[4][4];
          #pragma unroll
          for (int i = 0; i < 4; ++i) {
            const float4 v =
                *reinterpret_cast<const float4*>(&A1h[rt * 4 + i][k0 + k4]);
            av4[i][0] = v.x; av4[i][1] = v.y; av4[i][2] = v.z; av4[i][3] = v.w;
          }
          #pragma unroll
          for (int kk = 0; kk < 4; ++kk) {
            const float4* wrow = reinterpret_cast<const float4*>(&Wt[k4 + kk][0]);
            const float4 w0 = wrow[nt];
            const float4 w1 = wrow[32 + nt];
            const float wv8[8] = {w0.x, w0.y, w0.z, w0.w, w1.x, w1.y, w1.z, w1.w};
            #pragma unroll
            for (int i = 0; i < 4; ++i)
              #pragma unroll
              for (int c = 0; c < 8; ++c)
                Z[i][c] = fmaf(av4[i][kk], wv8[c], Z[i][c]);
          }
        }
        __syncthreads();  // Wt + A1h reads done
        if (t + 1 < NT_H) {
          #pragma unroll
          for (int j = 0; j < 4; ++j) {
            const int r = wv * 4 + j;
            stage16(W2 + (size_t)(c0 + k0 + KT + r) * H2 + lane * 4, &Wt[r][0]);
          }
        }
      }
    }

    // ================= layer 3 =================
    float part[4] = {0.f, 0.f, 0.f, 0.f};
    #pragma unroll
    for (int c = 0; c < 8; ++c) {
      const int col = (c < 4) ? nt * 4 + c : 124 + nt * 4 + c;
      const float w3v = W3[col];
      #pragma unroll
      for (int i = 0; i < 4; ++i)
        part[i] = fmaf(leaky(Z[i][c]), w3v, part[i]);
    }
    const float bb = B3[0];
    #pragma unroll
    for (int i = 0; i < 4; ++i) {
      float p = part[i];
      p += __shfl_xor(p, 1);
      p += __shfl_xor(p, 2);
      p += __shfl_xor(p, 4);
      p += __shfl_xor(p, 8);
      p += __shfl_xor(p, 16);
      const float z = leaky(p + bb);
      const float s = 1.f / (1.f + expf(-z));
      sigp[i] = tw ? sigp[i] * s : s;
    }
  }

  if (nt == 0) {
    #pragma unroll
    for (int i = 0; i < 4; ++i) out[r0 + rt * 4 + i] = sigp[i];
  }
}

extern "C" void kernel_launch(void* const* d_in, const int* in_sizes, int n_in,
                              void* d_out, int out_size, void* d_ws, size_t ws_size,
                              hipStream_t stream) {
  (void)in_sizes; (void)n_in; (void)out_size; (void)ws_size;
  const float* x    = (const float*)d_in[0];
  const int*   lens = (const int*)d_in[1];
  // d_in[2] = label_len (hard-coded 10)
  const float* cW1 = (const float*)d_in[3];
  const float* cb1 = (const float*)d_in[4];
  const float* cW2 = (const float*)d_in[5];
  const float* cb2 = (const float*)d_in[6];
  const float* cW3 = (const float*)d_in[7];
  const float* cb3 = (const float*)d_in[8];
  const float* vW1 = (const float*)d_in[9];
  const float* vb1 = (const float*)d_in[10];
  const float* vW2 = (const float*)d_in[11];
  const float* vb2 = (const float*)d_in[12];
  const float* vW3 = (const float*)d_in[13];
  const float* vb3 = (const float*)d_in[14];
  float* out  = (float*)d_out;
  float* hbuf = (float*)d_ws;  // [M_ROWS][D_DIM] f32 = 20 MB

  prefix_kernel<<<B_DIM / 4, 256, 0, stream>>>(x, lens, hbuf);
  tower_kernel<<<M_ROWS / 32, 256, 0, stream>>>(
      hbuf, cW1, cb1, cW2, cb2, cW3, cb3, vW1, vb1, vW2, vb2, vW3, vb3, out);
}

// Round 6
// 430.414 us; speedup vs baseline: 1.3781x; 1.3781x over previous
//
#include <hip/hip_runtime.h>
#include <math.h>

#define B_DIM 2048
#define D_DIM 256
#define H1 512
#define H2 256
#define LBL 10
#define M_ROWS (B_DIM * LBL)
#define HCH 256      // H1 half-chunk (layer1/layer2 fused per half)
#define A1_LD 260    // padded leading dim: 16B-aligned, spreads row-pairs across banks

__device__ __forceinline__ void acc4(float4& s, const float4 a) {
  s.x += a.x; s.y += a.y; s.z += a.z; s.w += a.w;
}

__device__ __forceinline__ float leaky(float v) { return v > 0.f ? v : 0.01f * v; }

// ---------------- Kernel A: prefix means -> h [B][LBL][D] ----------------
__global__ __launch_bounds__(256) void prefix_kernel(
    const float* __restrict__ x, const int* __restrict__ lens,
    float* __restrict__ h) {
  const int wv = threadIdx.x >> 6;
  const int lane = threadIdx.x & 63;
  const int b = blockIdx.x * 4 + wv;
  const int L = lens[b];
  const int Lm = L - LBL;
  const size_t ts = (size_t)(B_DIM * D_DIM / 4);
  const float4* xb = reinterpret_cast<const float4*>(x) + (size_t)b * (D_DIM / 4) + lane;
  float4 s0 = make_float4(0.f, 0.f, 0.f, 0.f), s1 = s0, s2 = s0, s3 = s0;
  int t = 0;
  for (; t + 8 <= Lm; t += 8) {
    float4 a0 = xb[(size_t)(t + 0) * ts], a1 = xb[(size_t)(t + 1) * ts];
    float4 a2 = xb[(size_t)(t + 2) * ts], a3 = xb[(size_t)(t + 3) * ts];
    float4 a4 = xb[(size_t)(t + 4) * ts], a5 = xb[(size_t)(t + 5) * ts];
    float4 a6 = xb[(size_t)(t + 6) * ts], a7 = xb[(size_t)(t + 7) * ts];
    acc4(s0, a0); acc4(s1, a1); acc4(s2, a2); acc4(s3, a3);
    acc4(s0, a4); acc4(s1, a5); acc4(s2, a6); acc4(s3, a7);
  }
  for (; t < Lm; ++t) acc4(s0, xb[(size_t)t * ts]);
  acc4(s0, s1); acc4(s2, s3); acc4(s0, s2);
  float4* hout = reinterpret_cast<float4*>(h) + (size_t)b * (LBL * D_DIM / 4) + lane;
  #pragma unroll
  for (int k = 0; k < LBL; ++k) {
    const int tt = Lm + k;
    acc4(s0, xb[(size_t)tt * ts]);
    const float inv = 1.0f / (float)(tt + 1);
    float4 o;
    o.x = s0.x * inv; o.y = s0.y * inv; o.z = s0.z * inv; o.w = s0.w * inv;
    hout[(size_t)k * (D_DIM / 4)] = o;
  }
}

// ---------------- Kernel B: one tower per blockIdx.y, 32 rows/block --------
// Exact Round-3 structure (best measured); tower loop hoisted to the grid so
// 1280 blocks are available to fill the machine (was 640 = 2.5 blocks/CU).
__global__ __launch_bounds__(256, 3) void tower_kernel(
    const float* __restrict__ h,
    const float* __restrict__ W1a, const float* __restrict__ b1a,
    const float* __restrict__ W2a, const float* __restrict__ b2a,
    const float* __restrict__ W3a, const float* __restrict__ b3a,
    const float* __restrict__ W1b, const float* __restrict__ b1b,
    const float* __restrict__ W2b, const float* __restrict__ b2b,
    const float* __restrict__ W3b, const float* __restrict__ b3b,
    float* __restrict__ sigbuf) {
  __shared__ float A1h[32][A1_LD];
  const int tid = threadIdx.x;
  const int rt = tid >> 5;   // row group (8): rows rt*4..rt*4+3
  const int nt = tid & 31;   // col group (32): 8 cols each
  const int r0 = blockIdx.x * 32;
  const int tw = blockIdx.y;
  const float* __restrict__ hr0 = h + (size_t)(r0 + rt * 4) * D_DIM;

  const float* __restrict__ W1 = tw ? W1b : W1a;
  const float* __restrict__ B1 = tw ? b1b : b1a;
  const float* __restrict__ W2 = tw ? W2b : W2a;
  const float* __restrict__ B2 = tw ? b2b : b2a;
  const float* __restrict__ W3 = tw ? W3b : W3a;
  const float* __restrict__ B3 = tw ? b3b : b3a;

  float Z[4][8];
  #pragma unroll
  for (int i = 0; i < 4; ++i)
    #pragma unroll
    for (int c = 0; c < 8; ++c) Z[i][c] = B2[nt * 8 + c];

  for (int half = 0; half < 2; ++half) {
    const int c0 = half * HCH;

    // ---- layer-1 half: a[4][8] = leaky(h[rows] @ W1[:, c0+nt*8 .. +7])
    float a[4][8];
    #pragma unroll
    for (int i = 0; i < 4; ++i)
      #pragma unroll
      for (int c = 0; c < 8; ++c) a[i][c] = B1[c0 + nt * 8 + c];

    #pragma unroll 2
    for (int k = 0; k < D_DIM; k += 4) {
      float hv[4][4];
      #pragma unroll
      for (int i = 0; i < 4; ++i) {
        const float4 v = *reinterpret_cast<const float4*>(hr0 + (size_t)i * D_DIM + k);
        hv[i][0] = v.x; hv[i][1] = v.y; hv[i][2] = v.z; hv[i][3] = v.w;
      }
      #pragma unroll
      for (int kk = 0; kk < 4; ++kk) {
        const float4* wr =
            reinterpret_cast<const float4*>(W1 + (size_t)(k + kk) * H1 + c0 + nt * 8);
        const float4 w0 = wr[0], w1 = wr[1];
        const float wv[8] = {w0.x, w0.y, w0.z, w0.w, w1.x, w1.y, w1.z, w1.w};
        #pragma unroll
        for (int i = 0; i < 4; ++i)
          #pragma unroll
          for (int c = 0; c < 8; ++c)
            a[i][c] = fmaf(hv[i][kk], wv[c], a[i][c]);
      }
    }
    #pragma unroll
    for (int i = 0; i < 4; ++i) {
      float4 s0, s1;
      s0.x = leaky(a[i][0]); s0.y = leaky(a[i][1]);
      s0.z = leaky(a[i][2]); s0.w = leaky(a[i][3]);
      s1.x = leaky(a[i][4]); s1.y = leaky(a[i][5]);
      s1.z = leaky(a[i][6]); s1.w = leaky(a[i][7]);
      float* dst = &A1h[rt * 4 + i][nt * 8];
      *reinterpret_cast<float4*>(dst) = s0;
      *reinterpret_cast<float4*>(dst + 4) = s1;
    }
    __syncthreads();

    // ---- layer-2 partial: Z += A1h[rows][0:256] @ W2[c0:c0+256, nt*8..+7]
    #pragma unroll 2
    for (int k = 0; k < HCH; k += 4) {
      float av[4][4];
      #pragma unroll
      for (int i = 0; i < 4; ++i) {
        const float4 v = *reinterpret_cast<const float4*>(&A1h[rt * 4 + i][k]);
        av[i][0] = v.x; av[i][1] = v.y; av[i][2] = v.z; av[i][3] = v.w;
      }
      #pragma unroll
      for (int kk = 0; kk < 4; ++kk) {
        const float4* wr =
            reinterpret_cast<const float4*>(W2 + (size_t)(c0 + k + kk) * H2 + nt * 8);
        const float4 w0 = wr[0], w1 = wr[1];
        const float wv[8] = {w0.x, w0.y, w0.z, w0.w, w1.x, w1.y, w1.z, w1.w};
        #pragma unroll
        for (int i = 0; i < 4; ++i)
          #pragma unroll
          for (int c = 0; c < 8; ++c)
            Z[i][c] = fmaf(av[i][kk], wv[c], Z[i][c]);
      }
    }
    __syncthreads();  // A1h reused by next half
  }

  // ---- layer 3: per-row dot(leaky(Z[row]), w3) reduced over nt
  float part[4] = {0.f, 0.f, 0.f, 0.f};
  #pragma unroll
  for (int c = 0; c < 8; ++c) {
    const float w3v = W3[nt * 8 + c];
    #pragma unroll
    for (int i = 0; i < 4; ++i)
      part[i] = fmaf(leaky(Z[i][c]), w3v, part[i]);
  }
  const float bb = B3[0];
  float sig[4];
  #pragma unroll
  for (int i = 0; i < 4; ++i) {
    float p = part[i];
    p += __shfl_xor(p, 1);
    p += __shfl_xor(p, 2);
    p += __shfl_xor(p, 4);
    p += __shfl_xor(p, 8);
    p += __shfl_xor(p, 16);
    const float z = leaky(p + bb);
    sig[i] = 1.f / (1.f + expf(-z));
  }

  if (nt == 0) {
    #pragma unroll
    for (int i = 0; i < 4; ++i)
      sigbuf[(size_t)tw * M_ROWS + r0 + rt * 4 + i] = sig[i];
  }
}

// ---------------- Kernel C: out = sig_ctr * sig_cvr ----------------
__global__ __launch_bounds__(256) void combine_kernel(
    const float* __restrict__ sigbuf, float* __restrict__ out) {
  const int i = blockIdx.x * 256 + threadIdx.x;
  out[i] = sigbuf[i] * sigbuf[M_ROWS + i];
}

extern "C" void kernel_launch(void* const* d_in, const int* in_sizes, int n_in,
                              void* d_out, int out_size, void* d_ws, size_t ws_size,
                              hipStream_t stream) {
  (void)in_sizes; (void)n_in; (void)out_size; (void)ws_size;
  const float* x    = (const float*)d_in[0];
  const int*   lens = (const int*)d_in[1];
  // d_in[2] = label_len (hard-coded 10)
  const float* cW1 = (const float*)d_in[3];
  const float* cb1 = (const float*)d_in[4];
  const float* cW2 = (const float*)d_in[5];
  const float* cb2 = (const float*)d_in[6];
  const float* cW3 = (const float*)d_in[7];
  const float* cb3 = (const float*)d_in[8];
  const float* vW1 = (const float*)d_in[9];
  const float* vb1 = (const float*)d_in[10];
  const float* vW2 = (const float*)d_in[11];
  const float* vb2 = (const float*)d_in[12];
  const float* vW3 = (const float*)d_in[13];
  const float* vb3 = (const float*)d_in[14];
  float* out  = (float*)d_out;
  float* hbuf = (float*)d_ws;                       // [M_ROWS][D_DIM] f32 = 20 MB
  float* sigbuf = hbuf + (size_t)M_ROWS * D_DIM;    // [2][M_ROWS] f32 = 160 KB

  prefix_kernel<<<B_DIM / 4, 256, 0, stream>>>(x, lens, hbuf);
  tower_kernel<<<dim3(M_ROWS / 32, 2), 256, 0, stream>>>(
      hbuf, cW1, cb1, cW2, cb2, cW3, cb3, vW1, vb1, vW2, vb2, vW3, vb3, sigbuf);
  combine_kernel<<<M_ROWS / 256, 256, 0, stream>>>(sigbuf, out);
}

// Round 7
// 233.741 us; speedup vs baseline: 2.5376x; 1.8414x over previous
//
#include <hip/hip_runtime.h>
#include <math.h>

#define B_DIM 2048
#define D_DIM 256
#define H1 512
#define H2 256
#define LBL 10
#define M_ROWS (B_DIM * LBL)
#define LD_A1 520  // bf16 elems; row stride 1040B = 65*16B (aligned), 260 dwords -> 2-way banks

typedef __attribute__((ext_vector_type(8))) short frag_ab;  // 8 bf16
typedef __attribute__((ext_vector_type(4))) float frag_cd;  // 4 f32

__device__ __forceinline__ float leaky(float v) { return v > 0.f ? v : 0.01f * v; }

__device__ __forceinline__ unsigned short f2bf(float f) {  // RNE
  union { float f; unsigned int u; } v;
  v.f = f;
  unsigned int r = v.u + 0x7FFFu + ((v.u >> 16) & 1u);
  return (unsigned short)(r >> 16);
}

__device__ __forceinline__ void acc4(float4& s, const float4 a) {
  s.x += a.x; s.y += a.y; s.z += a.z; s.w += a.w;
}

// ---------------- Kernel A: prefix means -> h bf16 [M_ROWS][256] ----------
__global__ __launch_bounds__(256) void prefix_kernel(
    const float* __restrict__ x, const int* __restrict__ lens,
    unsigned short* __restrict__ hb) {
  const int wv = threadIdx.x >> 6;
  const int lane = threadIdx.x & 63;
  const int b = blockIdx.x * 4 + wv;
  const int L = lens[b];
  const int Lm = L - LBL;
  const size_t ts = (size_t)(B_DIM * D_DIM / 4);
  const float4* xb = reinterpret_cast<const float4*>(x) + (size_t)b * (D_DIM / 4) + lane;
  float4 s0 = make_float4(0.f, 0.f, 0.f, 0.f), s1 = s0, s2 = s0, s3 = s0;
  int t = 0;
  for (; t + 8 <= Lm; t += 8) {
    float4 a0 = xb[(size_t)(t + 0) * ts], a1 = xb[(size_t)(t + 1) * ts];
    float4 a2 = xb[(size_t)(t + 2) * ts], a3 = xb[(size_t)(t + 3) * ts];
    float4 a4 = xb[(size_t)(t + 4) * ts], a5 = xb[(size_t)(t + 5) * ts];
    float4 a6 = xb[(size_t)(t + 6) * ts], a7 = xb[(size_t)(t + 7) * ts];
    acc4(s0, a0); acc4(s1, a1); acc4(s2, a2); acc4(s3, a3);
    acc4(s0, a4); acc4(s1, a5); acc4(s2, a6); acc4(s3, a7);
  }
  for (; t < Lm; ++t) acc4(s0, xb[(size_t)t * ts]);
  acc4(s0, s1); acc4(s2, s3); acc4(s0, s2);
  #pragma unroll
  for (int k = 0; k < LBL; ++k) {
    const int tt = Lm + k;
    acc4(s0, xb[(size_t)tt * ts]);
    const float inv = 1.0f / (float)(tt + 1);
    ushort4 o;
    o.x = f2bf(s0.x * inv); o.y = f2bf(s0.y * inv);
    o.z = f2bf(s0.z * inv); o.w = f2bf(s0.w * inv);
    *reinterpret_cast<ushort4*>(hb + (size_t)(b * LBL + k) * D_DIM + lane * 4) = o;
  }
}

// -------- transpose+cast: in [K][N] f32 -> out [N][K] bf16 ----------------
__global__ __launch_bounds__(256) void transp_kernel(
    const float* __restrict__ in, unsigned short* __restrict__ out,
    int kshift, int kmask, int nstride) {
  const int idx = blockIdx.x * 256 + threadIdx.x;
  const int n = idx >> kshift;
  const int k = idx & kmask;
  out[idx] = f2bf(in[(size_t)k * nstride + n]);
}

// ---------------- Kernel B: MFMA two-layer tower, 32 rows/block ------------
// 4 waves: w&1 -> row half (16 rows), w>>1 -> col half.
// Fragments (mfma_f32_16x16x32_bf16): A row / B col = lane&15,
// k = (lane>>4)*8 + j; C/D col = lane&15, row = (lane>>4)*4 + reg.
__global__ __launch_bounds__(256, 4) void tower_mfma(
    const unsigned short* __restrict__ hb,
    const unsigned short* __restrict__ W1T,  // [2][H1][D_DIM]
    const unsigned short* __restrict__ W2T,  // [2][H2][H1]
    const float* __restrict__ b1a, const float* __restrict__ b2a,
    const float* __restrict__ w3a, const float* __restrict__ b3a,
    const float* __restrict__ b1b, const float* __restrict__ b2b,
    const float* __restrict__ w3b, const float* __restrict__ b3b,
    float* __restrict__ sigbuf) {
  __shared__ unsigned short A1[32][LD_A1];
  __shared__ float part[2][32];
  const int tid = threadIdx.x;
  const int l = tid & 63;
  const int w = tid >> 6;
  const int lr = l & 15;   // tile row (A) / col (B,D)
  const int lg = l >> 4;   // k-group / D row-group
  const int rb = (w & 1) * 16;
  const int cbh = w >> 1;
  const int r0 = blockIdx.x * 32;
  const int tw = blockIdx.y;

  const unsigned short* __restrict__ W1t = W1T + (size_t)tw * H1 * D_DIM;
  const unsigned short* __restrict__ W2t = W2T + (size_t)tw * H2 * H1;
  const float* __restrict__ B1 = tw ? b1b : b1a;
  const float* __restrict__ B2 = tw ? b2b : b2a;
  const float* __restrict__ W3 = tw ? w3b : w3a;
  const float* __restrict__ B3 = tw ? b3b : b3a;

  // ===== layer 1: rows r0+rb..+15, cols cbh*256..+255, K=256 =====
  frag_cd acc1[16];
  #pragma unroll
  for (int n = 0; n < 16; ++n) {
    const float bv = B1[cbh * 256 + n * 16 + lr];
    acc1[n] = (frag_cd){bv, bv, bv, bv};
  }
  const unsigned short* arow = hb + (size_t)(r0 + rb + lr) * D_DIM;
  #pragma unroll
  for (int ks = 0; ks < D_DIM / 32; ++ks) {
    const frag_ab af = *reinterpret_cast<const frag_ab*>(arow + ks * 32 + lg * 8);
    #pragma unroll
    for (int n = 0; n < 16; ++n) {
      const frag_ab bf = *reinterpret_cast<const frag_ab*>(
          W1t + (size_t)(cbh * 256 + n * 16 + lr) * D_DIM + ks * 32 + lg * 8);
      acc1[n] = __builtin_amdgcn_mfma_f32_16x16x32_bf16(af, bf, acc1[n], 0, 0, 0);
    }
  }
  #pragma unroll
  for (int n = 0; n < 16; ++n)
    #pragma unroll
    for (int r = 0; r < 4; ++r)
      A1[rb + lg * 4 + r][cbh * 256 + n * 16 + lr] = f2bf(leaky(acc1[n][r]));
  __syncthreads();

  // ===== layer 2: rows rb..+15, cols cbh*128..+127, K=512 =====
  frag_cd acc2[8];
  #pragma unroll
  for (int n = 0; n < 8; ++n) {
    const float bv = B2[cbh * 128 + n * 16 + lr];
    acc2[n] = (frag_cd){bv, bv, bv, bv};
  }
  #pragma unroll
  for (int ks = 0; ks < H1 / 32; ++ks) {
    const frag_ab af = *reinterpret_cast<const frag_ab*>(&A1[rb + lr][ks * 32 + lg * 8]);
    #pragma unroll
    for (int n = 0; n < 8; ++n) {
      const frag_ab bf = *reinterpret_cast<const frag_ab*>(
          W2t + (size_t)(cbh * 128 + n * 16 + lr) * H1 + ks * 32 + lg * 8);
      acc2[n] = __builtin_amdgcn_mfma_f32_16x16x32_bf16(af, bf, acc2[n], 0, 0, 0);
    }
  }

  // ===== layer 3: dot(leaky(z2), w3), reduce cols =====
  float s[4] = {0.f, 0.f, 0.f, 0.f};
  #pragma unroll
  for (int n = 0; n < 8; ++n) {
    const float w3v = W3[cbh * 128 + n * 16 + lr];
    #pragma unroll
    for (int r = 0; r < 4; ++r)
      s[r] = fmaf(leaky(acc2[n][r]), w3v, s[r]);
  }
  #pragma unroll
  for (int r = 0; r < 4; ++r) {
    s[r] += __shfl_xor(s[r], 1);
    s[r] += __shfl_xor(s[r], 2);
    s[r] += __shfl_xor(s[r], 4);
    s[r] += __shfl_xor(s[r], 8);
  }
  if (lr == 0) {
    #pragma unroll
    for (int r = 0; r < 4; ++r) part[cbh][rb + lg * 4 + r] = s[r];
  }
  __syncthreads();
  if (tid < 32) {
    const float z = leaky(part[0][tid] + part[1][tid] + B3[0]);
    sigbuf[(size_t)tw * M_ROWS + r0 + tid] = 1.f / (1.f + expf(-z));
  }
}

// ---------------- Kernel C: out = sig_ctr * sig_cvr ----------------
__global__ __launch_bounds__(256) void combine_kernel(
    const float* __restrict__ sigbuf, float* __restrict__ out) {
  const int i = blockIdx.x * 256 + threadIdx.x;
  out[i] = sigbuf[i] * sigbuf[M_ROWS + i];
}

extern "C" void kernel_launch(void* const* d_in, const int* in_sizes, int n_in,
                              void* d_out, int out_size, void* d_ws, size_t ws_size,
                              hipStream_t stream) {
  (void)in_sizes; (void)n_in; (void)out_size; (void)ws_size;
  const float* x    = (const float*)d_in[0];
  const int*   lens = (const int*)d_in[1];
  // d_in[2] = label_len (hard-coded 10)
  const float* cW1 = (const float*)d_in[3];
  const float* cb1 = (const float*)d_in[4];
  const float* cW2 = (const float*)d_in[5];
  const float* cb2 = (const float*)d_in[6];
  const float* cW3 = (const float*)d_in[7];
  const float* cb3 = (const float*)d_in[8];
  const float* vW1 = (const float*)d_in[9];
  const float* vb1 = (const float*)d_in[10];
  const float* vW2 = (const float*)d_in[11];
  const float* vb2 = (const float*)d_in[12];
  const float* vW3 = (const float*)d_in[13];
  const float* vb3 = (const float*)d_in[14];
  float* out = (float*)d_out;

  // workspace layout (bytes)
  unsigned short* hb  = (unsigned short*)d_ws;                    // 20480*256*2 = 10.5 MB
  unsigned short* w1t = hb + (size_t)M_ROWS * D_DIM;              // 2*512*256 ushort
  unsigned short* w2t = w1t + 2 * H1 * D_DIM;                     // 2*256*512 ushort
  float* sigbuf = (float*)(w2t + 2 * H2 * H1);                    // 2*20480 f32

  prefix_kernel<<<B_DIM / 4, 256, 0, stream>>>(x, lens, hb);
  // W1 [256][512] -> W1T [512][256]: kshift=8, kmask=255, nstride=512
  transp_kernel<<<(H1 * D_DIM) / 256, 256, 0, stream>>>(cW1, w1t, 8, 255, H1);
  transp_kernel<<<(H1 * D_DIM) / 256, 256, 0, stream>>>(vW1, w1t + H1 * D_DIM, 8, 255, H1);
  // W2 [512][256] -> W2T [256][512]: kshift=9, kmask=511, nstride=256
  transp_kernel<<<(H2 * H1) / 256, 256, 0, stream>>>(cW2, w2t, 9, 511, H2);
  transp_kernel<<<(H2 * H1) / 256, 256, 0, stream>>>(vW2, w2t + H2 * H1, 9, 511, H2);

  tower_mfma<<<dim3(M_ROWS / 32, 2), 256, 0, stream>>>(
      hb, w1t, w2t, cb1, cb2, cW3, cb3, vb1, vb2, vW3, vb3, sigbuf);
  combine_kernel<<<M_ROWS / 256, 256, 0, stream>>>(sigbuf, out);
}

// Round 9
// 99.389 us; speedup vs baseline: 5.9679x; 2.3518x over previous
//
#include <hip/hip_runtime.h>
#include <math.h>

#define B_DIM 2048
#define D_DIM 256
#define H1 512
#define H2 256
#define LBL 10
#define M_ROWS (B_DIM * LBL)
#define LD_A1 520  // bf16 elems; row stride 1040B -> 2-way bank alias (free)
#define WSZ1 (H1 * D_DIM)  // 131072 elems per tower, layer1 pack
#define WSZ2 (H2 * H1)     // 131072 elems per tower, layer2 pack

typedef __attribute__((ext_vector_type(8))) short frag_ab;  // 8 bf16
typedef __attribute__((ext_vector_type(4))) float frag_cd;  // 4 f32

__device__ __forceinline__ float leaky(float v) { return v > 0.f ? v : 0.01f * v; }

__device__ __forceinline__ unsigned short f2bf(float f) {  // RNE
  union { float f; unsigned int u; } v;
  v.f = f;
  unsigned int r = v.u + 0x7FFFu + ((v.u >> 16) & 1u);
  return (unsigned short)(r >> 16);
}

__device__ __forceinline__ void acc4(float4& s, const float4 a) {
  s.x += a.x; s.y += a.y; s.z += a.z; s.w += a.w;
}

// ---------------- Kernel A: prefix means -> h bf16 [M_ROWS][256] ----------
__global__ __launch_bounds__(256) void prefix_kernel(
    const float* __restrict__ x, const int* __restrict__ lens,
    unsigned short* __restrict__ hb) {
  const int wv = threadIdx.x >> 6;
  const int lane = threadIdx.x & 63;
  const int b = blockIdx.x * 4 + wv;
  const int L = lens[b];
  const int Lm = L - LBL;
  const size_t ts = (size_t)(B_DIM * D_DIM / 4);
  const float4* xb = reinterpret_cast<const float4*>(x) + (size_t)b * (D_DIM / 4) + lane;
  float4 s0 = make_float4(0.f, 0.f, 0.f, 0.f), s1 = s0, s2 = s0, s3 = s0;
  int t = 0;
  for (; t + 8 <= Lm; t += 8) {
    float4 a0 = xb[(size_t)(t + 0) * ts], a1 = xb[(size_t)(t + 1) * ts];
    float4 a2 = xb[(size_t)(t + 2) * ts], a3 = xb[(size_t)(t + 3) * ts];
    float4 a4 = xb[(size_t)(t + 4) * ts], a5 = xb[(size_t)(t + 5) * ts];
    float4 a6 = xb[(size_t)(t + 6) * ts], a7 = xb[(size_t)(t + 7) * ts];
    acc4(s0, a0); acc4(s1, a1); acc4(s2, a2); acc4(s3, a3);
    acc4(s0, a4); acc4(s1, a5); acc4(s2, a6); acc4(s3, a7);
  }
  for (; t < Lm; ++t) acc4(s0, xb[(size_t)t * ts]);
  acc4(s0, s1); acc4(s2, s3); acc4(s0, s2);
  #pragma unroll
  for (int k = 0; k < LBL; ++k) {
    const int tt = Lm + k;
    acc4(s0, xb[(size_t)tt * ts]);
    const float inv = 1.0f / (float)(tt + 1);
    ushort4 o;
    o.x = f2bf(s0.x * inv); o.y = f2bf(s0.y * inv);
    o.z = f2bf(s0.z * inv); o.w = f2bf(s0.w * inv);
    *reinterpret_cast<ushort4*>(hb + (size_t)(b * LBL + k) * D_DIM + lane * 4) = o;
  }
}

// -------- pack W1 [256][512] f32 -> fragment-order bf16 -------------------
// P1[tower][cbh(2)][ks(8)][n(16)][l(64)][jj(8)]:
//   k = ks*32 + (l>>4)*8 + jj, col = cbh*256 + n*16 + (l&15)
__global__ __launch_bounds__(256) void pack1_kernel(
    const float* __restrict__ Wa, const float* __restrict__ Wb,
    unsigned short* __restrict__ P1) {
  const int idx = blockIdx.x * 256 + threadIdx.x;  // 0..16383
  const int tw = blockIdx.y;
  const float* __restrict__ in = tw ? Wb : Wa;
  const int l = idx & 63;
  const int n = (idx >> 6) & 15;
  const int ks = (idx >> 10) & 7;
  const int cbh = idx >> 13;
  const int col = cbh * 256 + n * 16 + (l & 15);
  const int k0 = ks * 32 + (l >> 4) * 8;
  unsigned short o[8];
  #pragma unroll
  for (int jj = 0; jj < 8; ++jj)
    o[jj] = f2bf(in[(size_t)(k0 + jj) * H1 + col]);
  ushort4* dst = reinterpret_cast<ushort4*>(P1 + (size_t)tw * WSZ1 + (size_t)idx * 8);
  dst[0] = make_ushort4(o[0], o[1], o[2], o[3]);
  dst[1] = make_ushort4(o[4], o[5], o[6], o[7]);
}

// -------- pack W2 [512][256] f32 -> fragment-order bf16 -------------------
// P2[tower][cbh(2)][ks(16)][n(8)][l(64)][jj(8)]:
//   k = ks*32 + (l>>4)*8 + jj, col = cbh*128 + n*16 + (l&15)
__global__ __launch_bounds__(256) void pack2_kernel(
    const float* __restrict__ Wa, const float* __restrict__ Wb,
    unsigned short* __restrict__ P2) {
  const int idx = blockIdx.x * 256 + threadIdx.x;  // 0..16383
  const int tw = blockIdx.y;
  const float* __restrict__ in = tw ? Wb : Wa;
  const int l = idx & 63;
  const int n = (idx >> 6) & 7;
  const int ks = (idx >> 9) & 15;
  const int cbh = idx >> 13;
  const int col = cbh * 128 + n * 16 + (l & 15);
  const int k0 = ks * 32 + (l >> 4) * 8;
  unsigned short o[8];
  #pragma unroll
  for (int jj = 0; jj < 8; ++jj)
    o[jj] = f2bf(in[(size_t)(k0 + jj) * H2 + col]);
  ushort4* dst = reinterpret_cast<ushort4*>(P2 + (size_t)tw * WSZ2 + (size_t)idx * 8);
  dst[0] = make_ushort4(o[0], o[1], o[2], o[3]);
  dst[1] = make_ushort4(o[4], o[5], o[6], o[7]);
}

// ---------------- Kernel B: MFMA two-layer tower, 32 rows/block ------------
// 4 waves: w&1 -> row half (16 rows), w>>1 -> col half. B-frags read from
// fragment-order packs: every load is lane-contiguous (64 x 16B = 1KB).
__global__ __launch_bounds__(256, 4) void tower_mfma(
    const unsigned short* __restrict__ hb,
    const unsigned short* __restrict__ P1,
    const unsigned short* __restrict__ P2,
    const float* __restrict__ b1a, const float* __restrict__ b2a,
    const float* __restrict__ w3a, const float* __restrict__ b3a,
    const float* __restrict__ b1b, const float* __restrict__ b2b,
    const float* __restrict__ w3b, const float* __restrict__ b3b,
    float* __restrict__ sigbuf) {
  __shared__ unsigned short A1[32][LD_A1];
  __shared__ float part[2][32];
  const int tid = threadIdx.x;
  const int l = tid & 63;
  const int w = tid >> 6;
  const int lr = l & 15;   // tile row (A) / col (B,D)
  const int lg = l >> 4;   // k-group / D row-group
  const int rb = (w & 1) * 16;
  const int cbh = w >> 1;
  const int r0 = blockIdx.x * 32;
  const int tw = blockIdx.y;

  const unsigned short* __restrict__ pb1 =
      P1 + (size_t)tw * WSZ1 + (size_t)cbh * (WSZ1 / 2) + (size_t)l * 8;
  const unsigned short* __restrict__ pb2 =
      P2 + (size_t)tw * WSZ2 + (size_t)cbh * (WSZ2 / 2) + (size_t)l * 8;
  const float* __restrict__ B1 = tw ? b1b : b1a;
  const float* __restrict__ B2 = tw ? b2b : b2a;
  const float* __restrict__ W3 = tw ? w3b : w3a;
  const float* __restrict__ B3 = tw ? b3b : b3a;

  // ===== layer 1: rows r0+rb..+15, cols cbh*256..+255, K=256 =====
  frag_cd acc1[16];
  #pragma unroll
  for (int n = 0; n < 16; ++n) {
    const float bv = B1[cbh * 256 + n * 16 + lr];
    acc1[n] = (frag_cd){bv, bv, bv, bv};
  }
  const unsigned short* arow = hb + (size_t)(r0 + rb + lr) * D_DIM;
  #pragma unroll
  for (int ks = 0; ks < D_DIM / 32; ++ks) {
    const frag_ab af = *reinterpret_cast<const frag_ab*>(arow + ks * 32 + lg * 8);
    #pragma unroll
    for (int n = 0; n < 16; ++n) {
      const frag_ab bf =
          *reinterpret_cast<const frag_ab*>(pb1 + (size_t)(ks * 16 + n) * 512);
      acc1[n] = __builtin_amdgcn_mfma_f32_16x16x32_bf16(af, bf, acc1[n], 0, 0, 0);
    }
  }
  #pragma unroll
  for (int n = 0; n < 16; ++n)
    #pragma unroll
    for (int r = 0; r < 4; ++r)
      A1[rb + lg * 4 + r][cbh * 256 + n * 16 + lr] = f2bf(leaky(acc1[n][r]));
  __syncthreads();

  // ===== layer 2: rows rb..+15, cols cbh*128..+127, K=512 =====
  frag_cd acc2[8];
  #pragma unroll
  for (int n = 0; n < 8; ++n) {
    const float bv = B2[cbh * 128 + n * 16 + lr];
    acc2[n] = (frag_cd){bv, bv, bv, bv};
  }
  #pragma unroll
  for (int ks = 0; ks < H1 / 32; ++ks) {
    const frag_ab af = *reinterpret_cast<const frag_ab*>(&A1[rb + lr][ks * 32 + lg * 8]);
    #pragma unroll
    for (int n = 0; n < 8; ++n) {
      const frag_ab bf =
          *reinterpret_cast<const frag_ab*>(pb2 + (size_t)(ks * 8 + n) * 512);
      acc2[n] = __builtin_amdgcn_mfma_f32_16x16x32_bf16(af, bf, acc2[n], 0, 0, 0);
    }
  }

  // ===== layer 3: dot(leaky(z2), w3), reduce cols =====
  float s[4] = {0.f, 0.f, 0.f, 0.f};
  #pragma unroll
  for (int n = 0; n < 8; ++n) {
    const float w3v = W3[cbh * 128 + n * 16 + lr];
    #pragma unroll
    for (int r = 0; r < 4; ++r)
      s[r] = fmaf(leaky(acc2[n][r]), w3v, s[r]);
  }
  #pragma unroll
  for (int r = 0; r < 4; ++r) {
    s[r] += __shfl_xor(s[r], 1);
    s[r] += __shfl_xor(s[r], 2);
    s[r] += __shfl_xor(s[r], 4);
    s[r] += __shfl_xor(s[r], 8);
  }
  if (lr == 0) {
    #pragma unroll
    for (int r = 0; r < 4; ++r) part[cbh][rb + lg * 4 + r] = s[r];
  }
  __syncthreads();
  if (tid < 32) {
    const float z = leaky(part[0][tid] + part[1][tid] + B3[0]);
    sigbuf[(size_t)tw * M_ROWS + r0 + tid] = 1.f / (1.f + expf(-z));
  }
}

// ---------------- Kernel C: out = sig_ctr * sig_cvr ----------------
__global__ __launch_bounds__(256) void combine_kernel(
    const float* __restrict__ sigbuf, float* __restrict__ out) {
  const int i = blockIdx.x * 256 + threadIdx.x;
  out[i] = sigbuf[i] * sigbuf[M_ROWS + i];
}

extern "C" void kernel_launch(void* const* d_in, const int* in_sizes, int n_in,
                              void* d_out, int out_size, void* d_ws, size_t ws_size,
                              hipStream_t stream) {
  (void)in_sizes; (void)n_in; (void)out_size; (void)ws_size;
  const float* x    = (const float*)d_in[0];
  const int*   lens = (const int*)d_in[1];
  // d_in[2] = label_len (hard-coded 10)
  const float* cW1 = (const float*)d_in[3];
  const float* cb1 = (const float*)d_in[4];
  const float* cW2 = (const float*)d_in[5];
  const float* cb2 = (const float*)d_in[6];
  const float* cW3 = (const float*)d_in[7];
  const float* cb3 = (const float*)d_in[8];
  const float* vW1 = (const float*)d_in[9];
  const float* vb1 = (const float*)d_in[10];
  const float* vW2 = (const float*)d_in[11];
  const float* vb2 = (const float*)d_in[12];
  const float* vW3 = (const float*)d_in[13];
  const float* vb3 = (const float*)d_in[14];
  float* out = (float*)d_out;

  // workspace layout
  unsigned short* hb = (unsigned short*)d_ws;          // 20480*256 bf16 = 10.5 MB
  unsigned short* p1 = hb + (size_t)M_ROWS * D_DIM;    // 2*131072 bf16
  unsigned short* p2 = p1 + 2 * WSZ1;                  // 2*131072 bf16
  float* sigbuf = (float*)(p2 + 2 * WSZ2);             // 2*20480 f32

  prefix_kernel<<<B_DIM / 4, 256, 0, stream>>>(x, lens, hb);
  pack1_kernel<<<dim3(WSZ1 / 8 / 256, 2), 256, 0, stream>>>(cW1, vW1, p1);
  pack2_kernel<<<dim3(WSZ2 / 8 / 256, 2), 256, 0, stream>>>(cW2, vW2, p2);

  tower_mfma<<<dim3(M_ROWS / 32, 2), 256, 0, stream>>>(
      hb, p1, p2, cb1, cb2, cW3, cb3, vb1, vb2, vW3, vb3, sigbuf);
  combine_kernel<<<M_ROWS / 256, 256, 0, stream>>>(sigbuf, out);
}